// Round 1
// baseline (354.804 us; speedup 1.0000x reference)
//
#include <hip/hip_runtime.h>

#define T_TOK 16384
#define IN_F  1024
#define OUT_F 4096
#define NH    32

// ---------------------------------------------------------------------------
// K1: w_t[h][o] = amp[o][h] * cosf(phase[o][h])   (transposed for GEMM2 staging)
// Writes coalesced (consecutive lanes -> consecutive o); reads lane-strided but
// phase/amp total only 1 MB -> L2 absorbs.
// ---------------------------------------------------------------------------
__global__ __launch_bounds__(256) void wreal_kernel(
    const float* __restrict__ phase, const float* __restrict__ amp,
    float* __restrict__ w_t)
{
    int idx = blockIdx.x * 256 + threadIdx.x;   // 0 .. 131071
    int o = idx & (OUT_F - 1);
    int h = idx >> 12;                          // idx / 4096
    float p = phase[o * NH + h];
    float a = amp[o * NH + h];
    w_t[h * OUT_F + o] = a * cosf(p);
}

// ---------------------------------------------------------------------------
// K2: res_t[h][t] = sum_i x[t][i] * basis[h][i]
// Block: 256 thr, 64 tokens, K-chunks of 128. Thread = 4 tokens x 2 harmonics.
// LDS strides 132 floats -> all compute reads are 2-way (free) bank patterns.
// ---------------------------------------------------------------------------
#define G1_TT 64
#define G1_KC 128
#define G1_S  132

__global__ __launch_bounds__(256) void resonance_kernel(
    const float* __restrict__ x,      // [16384][1024]
    const float* __restrict__ basis,  // [32][1024]
    float* __restrict__ res_t)        // [32][16384]
{
    __shared__ float xs[G1_TT * G1_S];   // 33.8 KB
    __shared__ float bs[NH * G1_S];      // 16.9 KB

    const int tid = threadIdx.x;
    const int t0  = blockIdx.x * G1_TT;
    const int ty  = tid >> 4;   // 0..15 : token group (4 tokens)
    const int tx  = tid & 15;   // h = tx, tx+16

    float acc[4][2] = {};

    for (int i0 = 0; i0 < IN_F; i0 += G1_KC) {
        // stage x tile: 64 rows x 128 floats = 2048 float4 / 256 thr = 8 each
        #pragma unroll
        for (int it = 0; it < 8; ++it) {
            int lin = it * 256 + tid;
            int r = lin >> 5, c = lin & 31;           // 32 float4 per row
            float4 v = *(const float4*)(x + (size_t)(t0 + r) * IN_F + i0 + 4 * c);
            *(float4*)(xs + r * G1_S + 4 * c) = v;
        }
        // stage basis tile: 32 x 128 = 1024 float4 / 256 thr = 4 each
        #pragma unroll
        for (int it = 0; it < 4; ++it) {
            int lin = it * 256 + tid;
            int r = lin >> 5, c = lin & 31;
            float4 v = *(const float4*)(basis + (size_t)r * IN_F + i0 + 4 * c);
            *(float4*)(bs + r * G1_S + 4 * c) = v;
        }
        __syncthreads();

        #pragma unroll 4
        for (int i = 0; i < G1_KC; i += 4) {
            float4 xa[4], bb[2];
            #pragma unroll
            for (int k = 0; k < 4; ++k)
                xa[k] = *(const float4*)(xs + (4 * ty + k) * G1_S + i);
            #pragma unroll
            for (int j = 0; j < 2; ++j)
                bb[j] = *(const float4*)(bs + (tx + 16 * j) * G1_S + i);
            #pragma unroll
            for (int k = 0; k < 4; ++k) {
                #pragma unroll
                for (int j = 0; j < 2; ++j) {
                    acc[k][j] += xa[k].x * bb[j].x;
                    acc[k][j] += xa[k].y * bb[j].y;
                    acc[k][j] += xa[k].z * bb[j].z;
                    acc[k][j] += xa[k].w * bb[j].w;
                }
            }
        }
        __syncthreads();
    }

    #pragma unroll
    for (int k = 0; k < 4; ++k)
        #pragma unroll
        for (int j = 0; j < 2; ++j)
            res_t[(size_t)(tx + 16 * j) * T_TOK + t0 + 4 * ty + k] = acc[k][j];
}

// ---------------------------------------------------------------------------
// K3: out[t][o] = sum_h res_t[h][t] * w_t[h][o]
// Block: 256 thr, tile 64 tokens x 128 outputs, K=32 fully in LDS (one stage).
// Thread = 4 tokens x 8 outputs (two float4 output groups). Per h-step:
// 3 ds_read_b128 -> 32 v_fmac. Strides 68/132 -> conflict-free / 2-way reads.
// Stores: float4, coalesced per 16-lane groups.
// ---------------------------------------------------------------------------
#define G2_TT 64
#define G2_OT 128
#define RS_S  68
#define WT_S  132

__global__ __launch_bounds__(256) void holo_out_kernel(
    const float* __restrict__ res_t,  // [32][16384]
    const float* __restrict__ w_t,    // [32][4096]
    float* __restrict__ out)          // [16384][4096]
{
    __shared__ float rs[NH * RS_S];   // 8.7 KB
    __shared__ float wl[NH * WT_S];   // 16.9 KB

    const int tid = threadIdx.x;
    const int o0  = blockIdx.x * G2_OT;
    const int t0  = blockIdx.y * G2_TT;
    const int ty  = tid >> 4;   // 0..15 : token group (4 tokens)
    const int tx  = tid & 15;   // output cols 4*tx and 64+4*tx

    // stage res_t tile: 32 rows x 64 floats = 512 float4 -> 2/thread
    #pragma unroll
    for (int it = 0; it < 2; ++it) {
        int lin = it * 256 + tid;                 // 0..511
        int r = lin >> 4, c = lin & 15;           // 16 float4 per row
        float4 v = *(const float4*)(res_t + (size_t)r * T_TOK + t0 + 4 * c);
        *(float4*)(rs + r * RS_S + 4 * c) = v;
    }
    // stage w_t tile: 32 rows x 128 floats = 1024 float4 -> 4/thread
    #pragma unroll
    for (int it = 0; it < 4; ++it) {
        int lin = it * 256 + tid;
        int r = lin >> 5, c = lin & 31;
        float4 v = *(const float4*)(w_t + (size_t)r * OUT_F + o0 + 4 * c);
        *(float4*)(wl + r * WT_S + 4 * c) = v;
    }
    __syncthreads();

    float acc[4][8] = {};
    #pragma unroll
    for (int h = 0; h < NH; ++h) {
        float4 rt = *(const float4*)(rs + h * RS_S + 4 * ty);
        float4 wa = *(const float4*)(wl + h * WT_S + 4 * tx);
        float4 wb = *(const float4*)(wl + h * WT_S + 64 + 4 * tx);
        float r4[4] = {rt.x, rt.y, rt.z, rt.w};
        float w8[8] = {wa.x, wa.y, wa.z, wa.w, wb.x, wb.y, wb.z, wb.w};
        #pragma unroll
        for (int k = 0; k < 4; ++k)
            #pragma unroll
            for (int j = 0; j < 8; ++j)
                acc[k][j] += r4[k] * w8[j];
    }

    #pragma unroll
    for (int k = 0; k < 4; ++k) {
        float* po = out + (size_t)(t0 + 4 * ty + k) * OUT_F + o0;
        *(float4*)(po + 4 * tx)      = make_float4(acc[k][0], acc[k][1], acc[k][2], acc[k][3]);
        *(float4*)(po + 64 + 4 * tx) = make_float4(acc[k][4], acc[k][5], acc[k][6], acc[k][7]);
    }
}

// ---------------------------------------------------------------------------
extern "C" void kernel_launch(void* const* d_in, const int* in_sizes, int n_in,
                              void* d_out, int out_size, void* d_ws, size_t ws_size,
                              hipStream_t stream)
{
    const float* x     = (const float*)d_in[0];  // [16384,1024]
    const float* basis = (const float*)d_in[1];  // [32,1024]
    const float* phase = (const float*)d_in[2];  // [4096,32]
    const float* amp   = (const float*)d_in[3];  // [4096,32]
    float* out = (float*)d_out;                  // [16384,4096] fp32

    float* res_t = (float*)d_ws;                       // 32*16384 floats = 2 MB
    float* w_t   = res_t + (size_t)NH * T_TOK;         // 32*4096 floats = 512 KB

    wreal_kernel<<<dim3((OUT_F * NH) / 256), dim3(256), 0, stream>>>(phase, amp, w_t);
    resonance_kernel<<<dim3(T_TOK / G1_TT), dim3(256), 0, stream>>>(x, basis, res_t);
    holo_out_kernel<<<dim3(OUT_F / G2_OT, T_TOK / G2_TT), dim3(256), 0, stream>>>(res_t, w_t, out);
}